// Round 11
// baseline (4153.910 us; speedup 1.0000x reference)
//
#include <hip/hip_runtime.h>
#include <stdint.h>
#include <cstdio>

#define B   256
#define T   1024
#define FIN 64
#define H   128
#define G4  512   // 4*H

typedef float  vf16 __attribute__((ext_vector_type(16)));
typedef __fp16 h2v  __attribute__((ext_vector_type(2)));

#define LOG2E 1.442695041f
__device__ __forceinline__ float fast_tanh(float x) {
    return fmaf(2.f, __builtin_amdgcn_rcpf(1.f + __builtin_amdgcn_exp2f(-2.f * LOG2E * x)), -1.f);
}

__device__ __forceinline__ uint32_t pkf(float a, float b) {
    union { h2v h; uint32_t u; } c;
    c.h.x = (__fp16)a; c.h.y = (__fp16)b;
    return c.u;
}
__device__ __forceinline__ uint32_t pkh(__fp16 a, __fp16 b) {
    union { h2v h; uint32_t u; } c;
    c.h.x = a; c.h.y = b;
    return c.u;
}
__device__ __forceinline__ h2v bch2(uint32_t u) {
    union { uint32_t u; h2v h; } c; c.u = u; return c.h;
}
__device__ __forceinline__ float dot2f(uint32_t w, uint32_t h, float acc) {
#if __has_builtin(__builtin_amdgcn_fdot2)
    return __builtin_amdgcn_fdot2(bch2(w), bch2(h), acc, false);
#else
    float r;
    asm("v_dot2_f32_f16 %0, %1, %2, %3" : "=v"(r) : "v"(w), "v"(h), "v"(acc));
    return r;
#endif
}

// ----------------------------------------------------------------------------
// prep: transpose W_ih -> WT[k][j], bias sums, zero states, pack W_hh -> f16
// Wp layout (matches scan LDS): u32 index i: kp2 = i>>10, r = (i&1023)>>1,
// d = i&1 -> pack(w[r][4kp2+2d], w[r][4kp2+2d+1]).
// ----------------------------------------------------------------------------
__global__ void prep_kernel(const float* __restrict__ W_ih0,
                            const float* __restrict__ b_ih0, const float* __restrict__ b_hh0,
                            const float* __restrict__ W_ih1,
                            const float* __restrict__ b_ih1, const float* __restrict__ b_hh1,
                            const float* __restrict__ W_hh0, const float* __restrict__ W_hh1,
                            float* __restrict__ WT0, float* __restrict__ WT1,
                            float* __restrict__ bsum0, float* __restrict__ bsum1,
                            uint32_t* __restrict__ Wp0, uint32_t* __restrict__ Wp1,
                            float* __restrict__ states /* 4*B*H */)
{
    int idx = blockIdx.x * blockDim.x + threadIdx.x;
    int n   = gridDim.x * blockDim.x;
    for (int i = idx; i < H * G4; i += n) { int k = i / G4, j = i % G4; WT1[i] = W_ih1[j * H + k]; }
    for (int i = idx; i < FIN * G4; i += n) { int k = i / G4, j = i % G4; WT0[i] = W_ih0[j * FIN + k]; }
    for (int i = idx; i < G4; i += n) { bsum0[i] = b_ih0[i] + b_hh0[i]; bsum1[i] = b_ih1[i] + b_hh1[i]; }
    for (int i = idx; i < 4 * B * H; i += n) states[i] = 0.f;
    for (int i = idx; i < 32768; i += n) {
        int kp2 = i >> 10, rem = i & 1023, r = rem >> 1, d = rem & 1;
        int k0 = (kp2 << 2) + (d << 1);
        Wp0[i] = pkf(W_hh0[r * H + k0], W_hh0[r * H + k0 + 1]);
        Wp1[i] = pkf(W_hh1[r * H + k0], W_hh1[r * H + k0 + 1]);
    }
}

// ----------------------------------------------------------------------------
// gx GEMM (R9 form, unchanged): 512 threads = 512 columns; 16 rows/block;
// K in 32-wide chunks; waves_per_eu(4).
// ----------------------------------------------------------------------------
#define GW(n)    ((n) < 16 ? u0[(n) & 15] : u1[(n) & 15])
#define GWS(n,v) do { if ((n) < 16) u0[(n) & 15] = (v); else u1[(n) & 15] = (v); } while (0)

#define GLD4(n) GWS((n), wp0[(long)(n) * G4]); GWS((n)+1, wp0[(long)((n)+1) * G4]); \
                GWS((n)+2, wp0[(long)((n)+2) * G4]); GWS((n)+3, wp0[(long)((n)+3) * G4]);

#define GMAC4(kk, r0) { \
    float4 v0 = *(const float4*)(x0 + (kk)); \
    float4 v1 = *(const float4*)(x1 + (kk)); \
    float4 v2 = *(const float4*)(x2 + (kk)); \
    float4 v3 = *(const float4*)(x3 + (kk)); \
    acc[(r0)+0] = fmaf(v0.x, GW(kk), acc[(r0)+0]); acc[(r0)+0] = fmaf(v0.y, GW((kk)+1), acc[(r0)+0]); \
    acc[(r0)+0] = fmaf(v0.z, GW((kk)+2), acc[(r0)+0]); acc[(r0)+0] = fmaf(v0.w, GW((kk)+3), acc[(r0)+0]); \
    acc[(r0)+1] = fmaf(v1.x, GW(kk), acc[(r0)+1]); acc[(r0)+1] = fmaf(v1.y, GW((kk)+1), acc[(r0)+1]); \
    acc[(r0)+1] = fmaf(v1.z, GW((kk)+2), acc[(r0)+1]); acc[(r0)+1] = fmaf(v1.w, GW((kk)+3), acc[(r0)+1]); \
    acc[(r0)+2] = fmaf(v2.x, GW(kk), acc[(r0)+2]); acc[(r0)+2] = fmaf(v2.y, GW((kk)+1), acc[(r0)+2]); \
    acc[(r0)+2] = fmaf(v2.z, GW((kk)+2), acc[(r0)+2]); acc[(r0)+2] = fmaf(v2.w, GW((kk)+3), acc[(r0)+2]); \
    acc[(r0)+3] = fmaf(v3.x, GW(kk), acc[(r0)+3]); acc[(r0)+3] = fmaf(v3.y, GW((kk)+1), acc[(r0)+3]); \
    acc[(r0)+3] = fmaf(v3.z, GW((kk)+2), acc[(r0)+3]); acc[(r0)+3] = fmaf(v3.w, GW((kk)+3), acc[(r0)+3]); }

#define GROW4(r0, kb) { \
    const float* __restrict__ x0 = xb + (long)((r0)+0) * sT + (kb); \
    const float* __restrict__ x1 = xb + (long)((r0)+1) * sT + (kb); \
    const float* __restrict__ x2 = xb + (long)((r0)+2) * sT + (kb); \
    const float* __restrict__ x3 = xb + (long)((r0)+3) * sT + (kb); \
    GMAC4(0,r0) GMAC4(4,r0) GMAC4(8,r0) GMAC4(12,r0) \
    GMAC4(16,r0) GMAC4(20,r0) GMAC4(24,r0) GMAC4(28,r0) }

#define GCHUNK(kb) { \
    vf16 u0, u1; \
    const float* __restrict__ wp0 = WT + (long)(kb) * G4 + j; \
    GLD4(0) GLD4(4) GLD4(8) GLD4(12) GLD4(16) GLD4(20) GLD4(24) GLD4(28) \
    GROW4(0,kb) GROW4(4,kb) GROW4(8,kb) GROW4(12,kb) }

template<int K>
__global__ __launch_bounds__(512) __attribute__((amdgpu_waves_per_eu(4)))
void gemm_gx(const float* __restrict__ X, long sB, long sT, int toff,
             const float* __restrict__ WT, const float* __restrict__ bsum,
             float* __restrict__ gx, int Tc)
{
    const int j    = threadIdx.x;
    const int m0   = blockIdx.x * 16;
    const int b    = m0 / Tc;
    const int tcl0 = m0 % Tc;

    const float bj = bsum[j];
    vf16 acc;
#pragma unroll
    for (int r = 0; r < 16; ++r) acc[r] = bj;

    const float* __restrict__ xb = X + (long)b * sB + (long)(toff + tcl0) * sT;
    float* __restrict__ gb = gx + (long)tcl0 * (B * G4) + (long)b * G4 + j;
    const long gstride = (long)B * G4;

    GCHUNK(0) GCHUNK(32)
    if constexpr (K == 128) { GCHUNK(64) GCHUNK(96) }

#pragma unroll
    for (int r = 0; r < 16; ++r) gb[(long)r * gstride] = acc[r];
}

// ----------------------------------------------------------------------------
// LSTM scan, LDS-streamed f16 weights + v_dot2_f32_f16.
// One block per batch (grid=256), 512 threads; thread owns gate row tid.
// Weights live in LDS (128 KB packed f16) laid out [kp2][row] so a wave's
// b64 reads cover 128 consecutive dwords (conflict-free). The in-loop
// __syncthreads() fences LDS -> the loads CANNOT be hoisted/register-
// allocated across iterations (kills the R4-R10 spill failure mode).
// h broadcast: packed f16 hi+lo pairs via readlane -> dot2 (compensated:
// only W carries f16 rounding error, ~2.5e-4 pre-activation).
// Update: threads tid<64 own element pairs (c in registers), write h1c
// directly to global; h_sh eliminated. 2 barriers/step.
// ----------------------------------------------------------------------------
__global__ __launch_bounds__(512)
void lstm_scan(const float* __restrict__ gx, const uint32_t* __restrict__ Wp,
               float* __restrict__ h_state, float* __restrict__ c_state,
               float* __restrict__ h1c,     /* null for layer 1 */
               float* __restrict__ h2last,  /* null for layer 0 */
               int Tc, int storeLast)
{
    __shared__ uint32_t wlds[32768];   // 128 KB packed f16 weights
    __shared__ float    gates[G4];
    __shared__ uint32_t hp_hi_l[64];
    __shared__ uint32_t hp_lo_l[64];

    const int tid  = threadIdx.x;   // gate row in [0, 512)
    const int b    = blockIdx.x;
    const int lane = tid & 63;

    // stage packed weights into LDS (coalesced b128 copies)
    {
        const uint4* __restrict__ src = (const uint4*)Wp;
        uint4* dst = (uint4*)wlds;
#pragma unroll
        for (int i = 0; i < 16; ++i) dst[tid + 512 * i] = src[tid + 512 * i];
    }

    // activation constants: rows [0,256)+[384,512) sigmoid; [256,384) tanh
    const bool istanh = (tid >= 2 * H && tid < 3 * H);
    const float kk = istanh ? (-2.f * LOG2E) : (-LOG2E);
    const float aa = istanh ? 2.f : 1.f;
    const float bb = istanh ? -1.f : 0.f;

    float c0v = 0.f, c1v = 0.f;
    if (tid < 64) {
        float ha = h_state[b * H + 2 * tid], hb = h_state[b * H + 2 * tid + 1];
        c0v = c_state[b * H + 2 * tid];
        c1v = c_state[b * H + 2 * tid + 1];
        __fp16 hh0 = (__fp16)ha, hh1 = (__fp16)hb;
        hp_hi_l[tid] = pkh(hh0, hh1);
        hp_lo_l[tid] = pkf(ha - (float)hh0, hb - (float)hh1);
    }
    __syncthreads();

    const long gstride = (long)B * G4;
    const float* __restrict__ gxp = gx + (long)b * G4 + tid;
    float gc = gxp[0];
    float gn = (Tc > 1) ? gxp[gstride] : 0.f;

    const uint32_t* wrow = wlds + 2 * tid;

    for (int t = 0; t < Tc; ++t) {
        float gn2 = (t + 2 < Tc) ? gxp[(long)(t + 2) * gstride] : 0.f;

        uint32_t hhi_u = hp_hi_l[lane];
        uint32_t hlo_u = hp_lo_l[lane];

        float a0 = gc, a1 = 0.f, a2 = 0.f, a3 = 0.f;
#pragma unroll
        for (int kp2 = 0; kp2 < 32; ++kp2) {
            uint2 wd = *(const uint2*)(wrow + (kp2 << 10));
            uint32_t shi0 = (uint32_t)__builtin_amdgcn_readlane((int)hhi_u, 2 * kp2);
            uint32_t slo0 = (uint32_t)__builtin_amdgcn_readlane((int)hlo_u, 2 * kp2);
            uint32_t shi1 = (uint32_t)__builtin_amdgcn_readlane((int)hhi_u, 2 * kp2 + 1);
            uint32_t slo1 = (uint32_t)__builtin_amdgcn_readlane((int)hlo_u, 2 * kp2 + 1);
            a0 = dot2f(wd.x, shi0, a0);
            a1 = dot2f(wd.x, slo0, a1);
            a2 = dot2f(wd.y, shi1, a2);
            a3 = dot2f(wd.y, slo1, a3);
        }
        float g = (a0 + a1) + (a2 + a3);

        float e = __builtin_amdgcn_exp2f(kk * g);
        float s = __builtin_amdgcn_rcpf(1.f + e);
        gates[tid] = fmaf(aa, s, bb);
        __syncthreads();   // gates ready; hp consumed by all

        if (tid < 64) {
            int u0 = 2 * tid, u1 = u0 + 1;
            float iv0 = gates[u0], fv0 = gates[H + u0], gv0 = gates[2 * H + u0], ov0 = gates[3 * H + u0];
            float iv1 = gates[u1], fv1 = gates[H + u1], gv1 = gates[2 * H + u1], ov1 = gates[3 * H + u1];
            c0v = fmaf(fv0, c0v, iv0 * gv0);
            c1v = fmaf(fv1, c1v, iv1 * gv1);
            float h0n = ov0 * fast_tanh(c0v);
            float h1n = ov1 * fast_tanh(c1v);
            if (h1c) *(float2*)&h1c[((long)b * Tc + t) * H + u0] = float2{h0n, h1n};
            if (storeLast && t == Tc - 1) *(float2*)&h2last[b * H + u0] = float2{h0n, h1n};
            if (t == Tc - 1) {
                *(float2*)&h_state[b * H + u0] = float2{h0n, h1n};
                *(float2*)&c_state[b * H + u0] = float2{c0v, c1v};
            }
            __fp16 hh0 = (__fp16)h0n, hh1 = (__fp16)h1n;
            hp_hi_l[tid] = pkh(hh0, hh1);
            hp_lo_l[tid] = pkf(h0n - (float)hh0, h1n - (float)hh1);
        }
        __syncthreads();   // hp ready for next step
        gc = gn; gn = gn2;
    }
}

// ----------------------------------------------------------------------------
// Dropout: JAX threefry2x32, jax_threefry_partitionable=True:
// counter (0, e), bits = y0 ^ y1, key (0, 42).
// ----------------------------------------------------------------------------
__device__ __forceinline__ uint32_t rotl32(uint32_t x, int r) { return (x << r) | (x >> (32 - r)); }

__global__ void dropout_kernel(const float* __restrict__ h2last, float* __restrict__ h2drop)
{
    int e = blockIdx.x * blockDim.x + threadIdx.x;
    if (e >= B * H) return;
    const uint32_t k0 = 0u, k1 = 42u, k2 = 0u ^ 42u ^ 0x1BD11BDAu;
    uint32_t x0 = 0u;
    uint32_t x1 = (uint32_t)e;
    x0 += k0; x1 += k1;
#define RG(ra,rb,rc,rd,ka,kb,inc) \
    x0 += x1; x1 = rotl32(x1, ra); x1 ^= x0; \
    x0 += x1; x1 = rotl32(x1, rb); x1 ^= x0; \
    x0 += x1; x1 = rotl32(x1, rc); x1 ^= x0; \
    x0 += x1; x1 = rotl32(x1, rd); x1 ^= x0; \
    x0 += ka; x1 += kb + inc;
    RG(13,15,26, 6, k1, k2, 1u)
    RG(17,29,16,24, k2, k0, 2u)
    RG(13,15,26, 6, k0, k1, 3u)
    RG(17,29,16,24, k1, k2, 4u)
    RG(13,15,26, 6, k2, k0, 5u)
#undef RG
    uint32_t bits = x0 ^ x1;
    float u = __uint_as_float((bits >> 9) | 0x3f800000u) - 1.0f;
    float a = h2last[e];
    h2drop[e] = (u >= 0.3f) ? (a / 0.7f) : 0.0f;
}

// ----------------------------------------------------------------------------
// Head: out[b][n] = b_out[n] + sum_u h2drop[b][u] * W_out[n][u]
// ----------------------------------------------------------------------------
__global__ void out_kernel(const float* __restrict__ h2drop, const float* __restrict__ W_out,
                           const float* __restrict__ b_out, float* __restrict__ out)
{
    int i = blockIdx.x * blockDim.x + threadIdx.x;
    if (i >= B * 2) return;
    int bb = i >> 1, n = i & 1;
    float acc = b_out[n];
    const float* __restrict__ hp = h2drop + (long)bb * H;
    const float* __restrict__ wp = W_out + (long)n * H;
#pragma unroll 4
    for (int u = 0; u < H; ++u) acc = fmaf(hp[u], wp[u], acc);
    out[i] = acc;
}

// ----------------------------------------------------------------------------
extern "C" void kernel_launch(void* const* d_in, const int* in_sizes, int n_in,
                              void* d_out, int out_size, void* d_ws, size_t ws_size,
                              hipStream_t stream)
{
    const float* x     = (const float*)d_in[0];
    const float* W_ih0 = (const float*)d_in[1];
    const float* W_hh0 = (const float*)d_in[2];
    const float* b_ih0 = (const float*)d_in[3];
    const float* b_hh0 = (const float*)d_in[4];
    const float* W_ih1 = (const float*)d_in[5];
    const float* W_hh1 = (const float*)d_in[6];
    const float* b_ih1 = (const float*)d_in[7];
    const float* b_hh1 = (const float*)d_in[8];
    const float* W_out = (const float*)d_in[9];
    const float* b_out = (const float*)d_in[10];
    float* out = (float*)d_out;

    char* ws = (char*)d_ws;
    size_t off = 0;
    auto alloc = [&](size_t bytes) { void* p = ws + off; off += (bytes + 255) & ~255ull; return p; };

    float* WT0    = (float*)alloc((size_t)FIN * G4 * 4);
    float* WT1    = (float*)alloc((size_t)H * G4 * 4);
    float* bsum0  = (float*)alloc((size_t)G4 * 4);
    float* bsum1  = (float*)alloc((size_t)G4 * 4);
    uint32_t* Wp0 = (uint32_t*)alloc((size_t)32768 * 4);
    uint32_t* Wp1 = (uint32_t*)alloc((size_t)32768 * 4);
    float* states = (float*)alloc((size_t)4 * B * H * 4);
    float* h0s = states, *c0s = states + B * H, *h1s = states + 2 * B * H, *c1s = states + 3 * B * H;
    float* h2last = (float*)alloc((size_t)B * H * 4);
    float* h2drop = (float*)alloc((size_t)B * H * 4);

    size_t fixed = off;
    int Tc = 16;
    const int cands[7] = {1024, 512, 256, 128, 64, 32, 16};
    for (int ci = 0; ci < 7; ++ci) {
        size_t need = fixed + (size_t)cands[ci] * ((size_t)B * H * 4 + (size_t)B * G4 * 4) + 8192;
        if (need <= ws_size) { Tc = cands[ci]; break; }
    }
    float* h1c = (float*)alloc((size_t)B * Tc * H * 4);
    float* gxb = (float*)alloc((size_t)Tc * B * G4 * 4);

    fprintf(stderr, "[kernel_launch] ws_size=%zu fixed=%zu Tc=%d total_used=%zu\n",
            ws_size, fixed, Tc, off);

    prep_kernel<<<512, 256, 0, stream>>>(W_ih0, b_ih0, b_hh0, W_ih1, b_ih1, b_hh1,
                                         W_hh0, W_hh1,
                                         WT0, WT1, bsum0, bsum1, Wp0, Wp1, states);

    const int nch = T / Tc;
    for (int c = 0; c < nch; ++c) {
        int t0 = c * Tc;
        gemm_gx<FIN><<<(B * Tc) / 16, 512, 0, stream>>>(x, (long)T * FIN, (long)FIN, t0,
                                                        WT0, bsum0, gxb, Tc);
        lstm_scan<<<B, 512, 0, stream>>>(gxb, Wp0, h0s, c0s, h1c, nullptr, Tc, 0);
        gemm_gx<H><<<(B * Tc) / 16, 512, 0, stream>>>(h1c, (long)Tc * H, (long)H, 0,
                                                      WT1, bsum1, gxb, Tc);
        lstm_scan<<<B, 512, 0, stream>>>(gxb, Wp1, h1s, c1s, nullptr, h2last, Tc,
                                         (t0 + Tc == T) ? 1 : 0);
    }

    dropout_kernel<<<128, 256, 0, stream>>>(h2last, h2drop);
    out_kernel<<<2, 256, 0, stream>>>(h2drop, W_out, b_out, out);
}